// Round 8
// baseline (51.735 us; speedup 1.0000x reference)
//
#include <hip/hip_runtime.h>
#include <hip/hip_bf16.h>

#define NG 128
#define NT 16

// ws float layout (tables 7680 floats, then partials):
//   gtab [128][8]  : {b0,b1,b2,b3, phi, 0,0,0}
//   mdp  [128][16] : md (planar)
//   emdp [128][16] : exp(md) (planar)
//   lgtab[128][20] : gammaln(phi+k)-gammaln(1+k)-gammaln(phi)+phi*ln(phi)
//   part [64][nsp] : [quarter*16+t][sample]
#define GTAB_OFF 0
#define MD_OFF   1024
#define EMD_OFF  3072
#define LG_OFF   5120
#define TAB_FLOATS 7680
#define PART_OFF 8192
#define LN2 0.6931471805599453f
#define L2E 1.4426950408889634f
#define EXP2F(x) __builtin_amdgcn_exp2f(x)

__global__ void setup_kernel(const float* __restrict__ delta,
                             const float* __restrict__ beta,
                             const float* __restrict__ phi,
                             const float* __restrict__ mo,
                             float* __restrict__ ws,
                             float* __restrict__ out) {
    const int g = threadIdx.x;
    if (g == 0) out[0] = 0.0f;
    if (g >= NG) return;

    const float lnfact[20] = {
        0.0f, 0.0f, 0.69314718f, 1.79175947f, 3.17805383f,
        4.78749174f, 6.57925121f, 8.52516132f, 10.60460286f, 12.80182744f,
        15.10441253f, 17.50230781f, 19.98721446f, 22.55216381f, 25.19122114f,
        27.89927134f, 30.67186007f, 33.50507341f, 36.39544517f, 39.33988415f};

    float ph = fminf(fmaxf(phi[g], 1.0f), 100.0f);
    float plp = ph * __logf(ph);

    ws[GTAB_OFF + g * 8 + 0] = beta[0 * NG + g];
    ws[GTAB_OFF + g * 8 + 1] = beta[1 * NG + g];
    ws[GTAB_OFF + g * 8 + 2] = beta[2 * NG + g];
    ws[GTAB_OFF + g * 8 + 3] = beta[3 * NG + g];
    ws[GTAB_OFF + g * 8 + 4] = ph;
    ws[GTAB_OFF + g * 8 + 5] = 0.0f;
    ws[GTAB_OFF + g * 8 + 6] = 0.0f;
    ws[GTAB_OFF + g * 8 + 7] = 0.0f;

#pragma unroll
    for (int t = 0; t < NT; ++t) {
        float md = mo[g * NT + t] * delta[g * NT + t];
        ws[MD_OFF  + g * 16 + t] = md;
        ws[EMD_OFF + g * 16 + t] = __expf(md);
    }

    float accn = 0.0f;
    ws[LG_OFF + g * 20 + 0] = plp;
#pragma unroll
    for (int k = 1; k < 20; ++k) {
        accn += __logf(ph + (float)(k - 1));
        ws[LG_OFF + g * 20 + k] = accn - lnfact[k] + plp;
    }
}

// Phase 1: block = 64 samples x 32 genes (quarter). 8 waves x 4 genes each.
// emd in REGISTERS (64 VGPR) -> inner (g,t) body = 2 fma + 1 log2, no memory.
__global__ __launch_bounds__(512, 4) void nb_phase1(const float* __restrict__ expr,
                                                    const float* __restrict__ cov,
                                                    const float* __restrict__ sfv,
                                                    const float* __restrict__ ws,
                                                    float* __restrict__ part_out,
                                                    int ns, int nsp) {
    __shared__ float s_tab[4352];   // staged quarter tables (1920 f); later red[4][64][17]
    float* __restrict__ s_gt  = s_tab;          // [32][8]   256 f
    float* __restrict__ s_mdp = s_tab + 256;    // [32][16]  512 f
    float* __restrict__ s_emd = s_tab + 768;    // [32][16]  512 f
    float* __restrict__ s_lg  = s_tab + 1280;   // [32][20]  640 f

    const int tid = threadIdx.x;
    const int tile = blockIdx.x >> 2;
    const int quarter = blockIdx.x & 3;

    if (tid < 64)
        ((float4*)s_gt)[tid] = ((const float4*)(ws + GTAB_OFF + quarter * 256))[tid];
    else if (tid < 192)
        ((float4*)s_mdp)[tid - 64] = ((const float4*)(ws + MD_OFF + quarter * 512))[tid - 64];
    else if (tid < 320)
        ((float4*)s_emd)[tid - 192] = ((const float4*)(ws + EMD_OFF + quarter * 512))[tid - 192];
    else if (tid < 480)
        ((float4*)s_lg)[tid - 320] = ((const float4*)(ws + LG_OFF + quarter * 640))[tid - 320];
    __syncthreads();

    const int lane = tid & 63;
    const int q = __builtin_amdgcn_readfirstlane(tid >> 6);  // wave id 0..7
    const int s = tile * 64 + lane;
    const bool valid = (s < ns);

    // preload this wave's 4 genes' exp(md) into registers (static indices)
    float emd[4][16];
#pragma unroll
    for (int a = 0; a < 4; ++a)
#pragma unroll
        for (int t = 0; t < NT; ++t)
            emd[a][t] = s_emd[(q * 4 + a) * 16 + t];

    float acc[NT];
#pragma unroll
    for (int t = 0; t < NT; ++t) acc[t] = 0.0f;
    float hacc = 0.0f;

    float4 cv = make_float4(0.f, 0.f, 0.f, 0.f);
    float sf = 1.0f;
    if (valid) {
        cv = *reinterpret_cast<const float4*>(cov + (size_t)s * 4);
        sf = sfv[s];
    }
    const float lsf  = __logf(sf);
    const float lsf2 = lsf * L2E;

    float4 kv = make_float4(0.f, 0.f, 0.f, 0.f);
    if (valid)
        kv = *reinterpret_cast<const float4*>(expr + (size_t)s * NG + quarter * 32 + q * 4);
    float kb[4] = {kv.x, kv.y, kv.z, kv.w};

#pragma unroll
    for (int a = 0; a < 4; ++a) {
        const int gl = q * 4 + a;
        const float b0 = s_gt[gl * 8 + 0];
        const float b1 = s_gt[gl * 8 + 1];
        const float b2 = s_gt[gl * 8 + 2];
        const float b3 = s_gt[gl * 8 + 3];
        const float ph = s_gt[gl * 8 + 4];

        float e = fmaf(b3, cv.w, fmaf(b2, cv.z, fmaf(b1, cv.y, b0 * cv.x)));
        float c = EXP2F(fmaf(e, L2E, lsf2));            // sf * exp(e)
        float kf = kb[a];
        float lg = s_lg[gl * 20 + (int)kf];             // per-lane gather
        hacc += fmaf(kf, lsf + e, lg);
        float nkp2 = -(kf + ph) * LN2;
#pragma unroll
        for (int t = 0; t < NT; ++t) {
            float v = fmaf(c, emd[a][t], ph);           // pure-register body
            acc[t] = fmaf(nkp2, __log2f(v), acc[t]);
        }
    }

    // end-phase: k*md terms (LDS broadcast, off the critical loop)
#pragma unroll
    for (int a = 0; a < 4; ++a) {
        const int gl = q * 4 + a;
        const float kf = kb[a];
#pragma unroll
        for (int t = 0; t < NT; ++t)
            acc[t] = fmaf(kf, s_mdp[gl * 16 + t], acc[t]);
    }
#pragma unroll
    for (int t = 0; t < NT; ++t) acc[t] += hacc;

    // tree reduction 8 -> 4 -> 2 -> 1; red aliases the (now dead) table LDS
    __syncthreads();
    float (*red)[64][17] = (float (*)[64][17])s_tab;

    if (q >= 4) {
#pragma unroll
        for (int t = 0; t < NT; ++t) red[q - 4][lane][t] = acc[t];
    }
    __syncthreads();
    if (q < 4) {
#pragma unroll
        for (int t = 0; t < NT; ++t) acc[t] += red[q][lane][t];
    }
    __syncthreads();
    if (q == 2 || q == 3) {
#pragma unroll
        for (int t = 0; t < NT; ++t) red[q - 2][lane][t] = acc[t];
    }
    __syncthreads();
    if (q < 2) {
#pragma unroll
        for (int t = 0; t < NT; ++t) acc[t] += red[q][lane][t];
    }
    __syncthreads();
    if (q == 1) {
#pragma unroll
        for (int t = 0; t < NT; ++t) red[0][lane][t] = acc[t];
    }
    __syncthreads();
    if (q == 0) {
#pragma unroll
        for (int t = 0; t < NT; ++t) {
            float v = acc[t] + red[0][lane][t];
            part_out[(size_t)(quarter * NT + t) * nsp + tile * 64 + lane] = v;
        }
    }
}

// Phase 2: per-sample combine of 4 quarter-partials + logsumexp + grand sum
__global__ __launch_bounds__(256) void nb_phase2(const float* __restrict__ part_in,
                                                 float* __restrict__ out,
                                                 int ns, int nsp) {
    const int s = blockIdx.x * 256 + threadIdx.x;
    float lp = 0.0f;
    if (s < ns) {
        float tot[NT];
#pragma unroll
        for (int t = 0; t < NT; ++t) tot[t] = 0.0f;
#pragma unroll
        for (int qt = 0; qt < 4; ++qt) {
#pragma unroll
            for (int t = 0; t < NT; ++t)
                tot[t] += part_in[(size_t)(qt * NT + t) * nsp + s];
        }
        float m = tot[0];
#pragma unroll
        for (int t = 1; t < NT; ++t) m = fmaxf(m, tot[t]);
        float sum = 0.0f;
#pragma unroll
        for (int t = 0; t < NT; ++t) sum += __expf(tot[t] - m);
        lp = m + __logf(sum);
    }
#pragma unroll
    for (int off = 32; off > 0; off >>= 1) lp += __shfl_down(lp, off);
    __shared__ float r[4];
    if ((threadIdx.x & 63) == 0) r[threadIdx.x >> 6] = lp;
    __syncthreads();
    if (threadIdx.x == 0) atomicAdd(out, r[0] + r[1] + r[2] + r[3]);
}

// Fallback (ws too small for partials): single-phase, full tables in LDS.
__global__ __launch_bounds__(512) void nb_single(const float* __restrict__ expr,
                                                 const float* __restrict__ cov,
                                                 const float* __restrict__ sfv,
                                                 const float* __restrict__ ws,
                                                 float* __restrict__ out,
                                                 int ns) {
    __shared__ float s_tab[TAB_FLOATS];
    const int tid = threadIdx.x;
#pragma unroll
    for (int i = 0; i < 4; ++i) {
        int idx = tid + i * 512;
        if (idx < TAB_FLOATS / 4)
            *(float4*)&s_tab[idx * 4] = *(const float4*)(ws + idx * 4);
    }
    __syncthreads();

    const float* __restrict__ s_gt  = s_tab + GTAB_OFF;
    const float* __restrict__ s_mdp = s_tab + MD_OFF;
    const float* __restrict__ s_emd = s_tab + EMD_OFF;
    const float* __restrict__ s_lg  = s_tab + LG_OFF;

    const int lane = tid & 63;
    const int q = __builtin_amdgcn_readfirstlane(tid >> 6);
    const int s = blockIdx.x * 64 + lane;
    const bool valid = (s < ns);

    float acc[NT];
#pragma unroll
    for (int t = 0; t < NT; ++t) acc[t] = 0.0f;
    float hacc = 0.0f;

    float4 cv = make_float4(0.f, 0.f, 0.f, 0.f);
    float sf = 1.0f;
    if (valid) {
        cv = *reinterpret_cast<const float4*>(cov + (size_t)s * 4);
        sf = sfv[s];
    }
    const float lsf  = __logf(sf);
    const float lsf2 = lsf * L2E;
    const int g0 = q * 16;

    for (int g4 = 0; g4 < 4; ++g4) {
        float4 kvv = make_float4(0.f, 0.f, 0.f, 0.f);
        if (valid)
            kvv = *reinterpret_cast<const float4*>(expr + (size_t)s * NG + g0 + g4 * 4);
        float kfv[4] = {kvv.x, kvv.y, kvv.z, kvv.w};
#pragma unroll
        for (int j = 0; j < 4; ++j) {
            const int g = g0 + g4 * 4 + j;
            const float b0 = s_gt[g * 8 + 0];
            const float b1 = s_gt[g * 8 + 1];
            const float b2 = s_gt[g * 8 + 2];
            const float b3 = s_gt[g * 8 + 3];
            const float ph = s_gt[g * 8 + 4];

            float e = fmaf(b3, cv.w, fmaf(b2, cv.z, fmaf(b1, cv.y, b0 * cv.x)));
            float c = EXP2F(fmaf(e, L2E, lsf2));
            float kf = kfv[j];
            float lg = s_lg[g * 20 + (int)kf];
            hacc += fmaf(kf, lsf + e, lg);
            float nkp2 = -(kf + ph) * LN2;
#pragma unroll
            for (int t = 0; t < NT; ++t) {
                float v = fmaf(c, s_emd[g * 16 + t], ph);
                acc[t] = fmaf(nkp2, __log2f(v), fmaf(kf, s_mdp[g * 16 + t], acc[t]));
            }
        }
    }
#pragma unroll
    for (int t = 0; t < NT; ++t) acc[t] += hacc;

    float (*red)[64][17] = (float (*)[64][17])s_tab;
    __syncthreads();
    if (q >= 4) {
#pragma unroll
        for (int t = 0; t < NT; ++t) red[q - 4][lane][t] = acc[t];
    }
    __syncthreads();
    if (q < 4) {
#pragma unroll
        for (int t = 0; t < NT; ++t) acc[t] += red[q][lane][t];
    }
    __syncthreads();
    if (q == 2 || q == 3) {
#pragma unroll
        for (int t = 0; t < NT; ++t) red[q - 2][lane][t] = acc[t];
    }
    __syncthreads();
    if (q < 2) {
#pragma unroll
        for (int t = 0; t < NT; ++t) acc[t] += red[q][lane][t];
    }
    __syncthreads();
    if (q == 1) {
#pragma unroll
        for (int t = 0; t < NT; ++t) red[0][lane][t] = acc[t];
    }
    __syncthreads();
    if (q == 0) {
        float m = -1e30f;
#pragma unroll
        for (int t = 0; t < NT; ++t) {
            acc[t] += red[0][lane][t];
            m = fmaxf(m, acc[t]);
        }
        float sum = 0.0f;
#pragma unroll
        for (int t = 0; t < NT; ++t) sum += __expf(acc[t] - m);
        float lp = m + __logf(sum);
        if (!valid) lp = 0.0f;
#pragma unroll
        for (int off = 32; off > 0; off >>= 1) lp += __shfl_down(lp, off);
        if (lane == 0) atomicAdd(out, lp);
    }
}

extern "C" void kernel_launch(void* const* d_in, const int* in_sizes, int n_in,
                              void* d_out, int out_size, void* d_ws, size_t ws_size,
                              hipStream_t stream) {
    const float* delta = (const float*)d_in[0];
    const float* beta  = (const float*)d_in[1];
    const float* phi   = (const float*)d_in[2];
    const float* expr  = (const float*)d_in[3];
    const float* cov   = (const float*)d_in[4];
    const float* sf    = (const float*)d_in[5];
    const float* mo    = (const float*)d_in[6];
    float* out = (float*)d_out;
    float* ws  = (float*)d_ws;
    const int ns = in_sizes[5];

    setup_kernel<<<1, 128, 0, stream>>>(delta, beta, phi, mo, ws, out);

    const int tiles = (ns + 63) / 64;
    const int nsp = tiles * 64;
    const size_t need = ((size_t)PART_OFF + 64ull * (size_t)nsp) * 4ull;

    if (ws_size >= need) {
        float* part = ws + PART_OFF;
        nb_phase1<<<tiles * 4, 512, 0, stream>>>(expr, cov, sf, ws, part, ns, nsp);
        nb_phase2<<<(ns + 255) / 256, 256, 0, stream>>>(part, out, ns, nsp);
    } else {
        nb_single<<<tiles, 512, 0, stream>>>(expr, cov, sf, ws, out, ns);
    }
}

// Round 9
// 36.553 us; speedup vs baseline: 1.4154x; 1.4154x over previous
//
#include <hip/hip_runtime.h>
#include <hip/hip_bf16.h>

#define NG 128
#define NT 16

// ws float layout (tables contiguous, 7680 floats):
//   gtab [128][8]  : {b0,b1,b2,b3, phi, 0,0,0}
//   mdp  [128][16] : md (planar)
//   emdp [128][16] : exp(md) (planar)
//   lgtab[128][20] : gammaln(phi+k)-gammaln(1+k)-gammaln(phi)+phi*ln(phi)
#define GTAB_OFF 0
#define MD_OFF   1024
#define EMD_OFF  3072
#define LG_OFF   5120
#define TAB_FLOATS 7680
#define LN2 0.6931471805599453f
#define L2E 1.4426950408889634f
#define EXP2F(x) __builtin_amdgcn_exp2f(x)

__global__ void setup_kernel(const float* __restrict__ delta,
                             const float* __restrict__ beta,
                             const float* __restrict__ phi,
                             const float* __restrict__ mo,
                             float* __restrict__ ws,
                             float* __restrict__ out) {
    const int g = threadIdx.x;
    if (g == 0) out[0] = 0.0f;   // deterministic re-init every call
    if (g >= NG) return;

    const float lnfact[20] = {
        0.0f, 0.0f, 0.69314718f, 1.79175947f, 3.17805383f,
        4.78749174f, 6.57925121f, 8.52516132f, 10.60460286f, 12.80182744f,
        15.10441253f, 17.50230781f, 19.98721446f, 22.55216381f, 25.19122114f,
        27.89927134f, 30.67186007f, 33.50507341f, 36.39544517f, 39.33988415f};

    float ph = fminf(fmaxf(phi[g], 1.0f), 100.0f);
    float plp = ph * __logf(ph);

    ws[GTAB_OFF + g * 8 + 0] = beta[0 * NG + g];
    ws[GTAB_OFF + g * 8 + 1] = beta[1 * NG + g];
    ws[GTAB_OFF + g * 8 + 2] = beta[2 * NG + g];
    ws[GTAB_OFF + g * 8 + 3] = beta[3 * NG + g];
    ws[GTAB_OFF + g * 8 + 4] = ph;
    ws[GTAB_OFF + g * 8 + 5] = 0.0f;
    ws[GTAB_OFF + g * 8 + 6] = 0.0f;
    ws[GTAB_OFF + g * 8 + 7] = 0.0f;

#pragma unroll
    for (int t = 0; t < NT; ++t) {
        float md = mo[g * NT + t] * delta[g * NT + t];
        ws[MD_OFF  + g * 16 + t] = md;
        ws[EMD_OFF + g * 16 + t] = __expf(md);
    }

    float accn = 0.0f;
    ws[LG_OFF + g * 20 + 0] = plp;
#pragma unroll
    for (int k = 1; k < 20; ++k) {
        accn += __logf(ph + (float)(k - 1));
        ws[LG_OFF + g * 20 + k] = accn - lnfact[k] + plp;
    }
}

// Single-phase: block = 64 samples x 128 genes, 8 waves x 16 genes each.
// Per gene: wide b128 LDS reads into registers, log-chain body pure-register,
// k*md tail off the log chain. Gene loop unrolled 2x for latency overlap.
__global__ __launch_bounds__(512) void nb_main(const float* __restrict__ expr,
                                               const float* __restrict__ cov,
                                               const float* __restrict__ sfv,
                                               const float* __restrict__ ws,
                                               float* __restrict__ out,
                                               int ns) {
    __shared__ float s_tab[TAB_FLOATS];          // 30.7 KB

    const int tid = threadIdx.x;
#pragma unroll
    for (int i = 0; i < 4; ++i) {
        int idx = tid + i * 512;
        if (idx < TAB_FLOATS / 4)
            *(float4*)&s_tab[idx * 4] = *(const float4*)(ws + idx * 4);
    }
    __syncthreads();

    const float* __restrict__ s_gt  = s_tab + GTAB_OFF;   // [128][8]
    const float* __restrict__ s_mdp = s_tab + MD_OFF;     // [128][16]
    const float* __restrict__ s_emd = s_tab + EMD_OFF;    // [128][16]
    const float* __restrict__ s_lg  = s_tab + LG_OFF;     // [128][20]

    const int lane = tid & 63;
    const int q = __builtin_amdgcn_readfirstlane(tid >> 6);  // wave id 0..7
    const int s = blockIdx.x * 64 + lane;
    const bool valid = (s < ns);

    float acc[NT];
#pragma unroll
    for (int t = 0; t < NT; ++t) acc[t] = 0.0f;
    float hacc = 0.0f;

    float4 cv = make_float4(0.f, 0.f, 0.f, 0.f);
    float sf = 1.0f;
    if (valid) {
        cv = *reinterpret_cast<const float4*>(cov + (size_t)s * 4);
        sf = sfv[s];
    }
    const float lsf  = __logf(sf);
    const float lsf2 = lsf * L2E;

    const int g0 = q * 16;   // wave-uniform gene strip (16 genes)

    // preload all 16 k values for this lane's sample
    float kb[16];
#pragma unroll
    for (int g4 = 0; g4 < 4; ++g4) {
        float4 kv = make_float4(0.f, 0.f, 0.f, 0.f);
        if (valid)
            kv = *reinterpret_cast<const float4*>(expr + (size_t)s * NG + g0 + g4 * 4);
        kb[g4 * 4 + 0] = kv.x; kb[g4 * 4 + 1] = kv.y;
        kb[g4 * 4 + 2] = kv.z; kb[g4 * 4 + 3] = kv.w;
    }

#pragma unroll 2
    for (int gg = 0; gg < 16; ++gg) {
        const int g = g0 + gg;
        // wide table reads into registers (broadcast, prefetchable)
        float4 bv = *(const float4*)&s_gt[g * 8];          // b0..b3
        float  ph = s_gt[g * 8 + 4];
        float4 ev0 = *(const float4*)&s_emd[g * 16 + 0];
        float4 ev1 = *(const float4*)&s_emd[g * 16 + 4];
        float4 ev2 = *(const float4*)&s_emd[g * 16 + 8];
        float4 ev3 = *(const float4*)&s_emd[g * 16 + 12];
        float4 mv0 = *(const float4*)&s_mdp[g * 16 + 0];
        float4 mv1 = *(const float4*)&s_mdp[g * 16 + 4];
        float4 mv2 = *(const float4*)&s_mdp[g * 16 + 8];
        float4 mv3 = *(const float4*)&s_mdp[g * 16 + 12];

        float e = fmaf(bv.w, cv.w, fmaf(bv.z, cv.z, fmaf(bv.y, cv.y, bv.x * cv.x)));
        float c = EXP2F(fmaf(e, L2E, lsf2));               // sf * exp(e)
        float kf = kb[gg];
        float lg = s_lg[g * 20 + (int)kf];                 // per-lane gather
        hacc += fmaf(kf, lsf + e, lg);
        float nkp2 = -(kf + ph) * LN2;

        const float ee[16] = {ev0.x, ev0.y, ev0.z, ev0.w, ev1.x, ev1.y, ev1.z, ev1.w,
                              ev2.x, ev2.y, ev2.z, ev2.w, ev3.x, ev3.y, ev3.z, ev3.w};
        const float mm[16] = {mv0.x, mv0.y, mv0.z, mv0.w, mv1.x, mv1.y, mv1.z, mv1.w,
                              mv2.x, mv2.y, mv2.z, mv2.w, mv3.x, mv3.y, mv3.z, mv3.w};
#pragma unroll
        for (int t = 0; t < NT; ++t) {
            float v = fmaf(c, ee[t], ph);                  // mu + phi (registers)
            acc[t] = fmaf(nkp2, __log2f(v), acc[t]);       // log chain, 2 ops
        }
#pragma unroll
        for (int t = 0; t < NT; ++t)
            acc[t] = fmaf(kf, mm[t], acc[t]);              // k*md tail (registers)
    }
#pragma unroll
    for (int t = 0; t < NT; ++t) acc[t] += hacc;

    // ---- tree reduction 8 -> 4 -> 2 -> 1 through LDS aliased onto s_tab ----
    float (*red)[64][17] = (float (*)[64][17])s_tab;   // 4*64*17 = 4352 <= 7680
    __syncthreads();                                   // tables dead from here

    if (q >= 4) {
#pragma unroll
        for (int t = 0; t < NT; ++t) red[q - 4][lane][t] = acc[t];
    }
    __syncthreads();
    if (q < 4) {
#pragma unroll
        for (int t = 0; t < NT; ++t) acc[t] += red[q][lane][t];
    }
    __syncthreads();
    if (q == 2 || q == 3) {
#pragma unroll
        for (int t = 0; t < NT; ++t) red[q - 2][lane][t] = acc[t];
    }
    __syncthreads();
    if (q < 2) {
#pragma unroll
        for (int t = 0; t < NT; ++t) acc[t] += red[q][lane][t];
    }
    __syncthreads();
    if (q == 1) {
#pragma unroll
        for (int t = 0; t < NT; ++t) red[0][lane][t] = acc[t];
    }
    __syncthreads();
    if (q == 0) {
        float m = -1e30f;
#pragma unroll
        for (int t = 0; t < NT; ++t) {
            acc[t] += red[0][lane][t];
            m = fmaxf(m, acc[t]);
        }
        float sum = 0.0f;
#pragma unroll
        for (int t = 0; t < NT; ++t) sum += __expf(acc[t] - m);
        float lp = m + __logf(sum);
        if (!valid) lp = 0.0f;
#pragma unroll
        for (int off = 32; off > 0; off >>= 1) lp += __shfl_down(lp, off);
        if (lane == 0) atomicAdd(out, lp);
    }
}

extern "C" void kernel_launch(void* const* d_in, const int* in_sizes, int n_in,
                              void* d_out, int out_size, void* d_ws, size_t ws_size,
                              hipStream_t stream) {
    const float* delta = (const float*)d_in[0];
    const float* beta  = (const float*)d_in[1];
    const float* phi   = (const float*)d_in[2];
    const float* expr  = (const float*)d_in[3];
    const float* cov   = (const float*)d_in[4];
    const float* sf    = (const float*)d_in[5];
    const float* mo    = (const float*)d_in[6];
    float* out = (float*)d_out;
    float* ws  = (float*)d_ws;
    const int ns = in_sizes[5];

    setup_kernel<<<1, 128, 0, stream>>>(delta, beta, phi, mo, ws, out);

    const int tiles = (ns + 63) / 64;
    nb_main<<<tiles, 512, 0, stream>>>(expr, cov, sf, ws, out, ns);
}